// Round 4
// baseline (488.714 us; speedup 1.0000x reference)
//
#include <hip/hip_runtime.h>
#include <hip/hip_bf16.h>
#include <math.h>

typedef __bf16 bf16x8 __attribute__((ext_vector_type(8)));
typedef __bf16 bf16x4 __attribute__((ext_vector_type(4)));
typedef unsigned short u16x8 __attribute__((ext_vector_type(8)));
typedef float  f32x4  __attribute__((ext_vector_type(4)));

constexpr int kS   = 2048;
constexpr int kH   = 4096;
constexpr int kNH  = 32;
constexpr int kNKV = 8;
constexpr int kHD  = 128;
constexpr int kQKV = kH + 2 * kNKV * kHD;   // 6144: [Q 4096 | K 1024 | V 1024]
constexpr int kKOff = kH;                    // 4096
constexpr int kVOff = kH + kNKV * kHD;       // 5120

// ---------------------------------------------------------------- generic cast
__global__ void cast_bf16(const float* __restrict__ in, __bf16* __restrict__ out, int n4) {
    int i = blockIdx.x * blockDim.x + threadIdx.x;
    if (i < n4) {
        float4 f = ((const float4*)in)[i];
        bf16x4 o;
        o[0] = (__bf16)f.x; o[1] = (__bf16)f.y; o[2] = (__bf16)f.z; o[3] = (__bf16)f.w;
        ((bf16x4*)out)[i] = o;
    }
}

// ---------------------------------------------------------------- fused cast: x -> xb, wq|wk|wv -> wqkv
__global__ void cast_all(const float* __restrict__ x, const float* __restrict__ wq,
                         const float* __restrict__ wk, const float* __restrict__ wv,
                         __bf16* __restrict__ xb, __bf16* __restrict__ wqkv) {
    int i = blockIdx.x * 256 + threadIdx.x;
    float4 f;
    __bf16* dst;
    int di;
    if (i < (1 << 21)) {
        f = ((const float4*)x)[i];
        dst = xb; di = i;
    } else {
        int j = i - (1 << 21);
        const float4* s = (j < (1 << 22)) ? ((const float4*)wq + j)
                        : (j < (5 << 20)) ? ((const float4*)wk + (j - (1 << 22)))
                                          : ((const float4*)wv + (j - (5 << 20)));
        f = *s;
        dst = wqkv; di = j;
    }
    bf16x4 o;
    o[0] = (__bf16)f.x; o[1] = (__bf16)f.y; o[2] = (__bf16)f.z; o[3] = (__bf16)f.w;
    ((bf16x4*)dst)[di] = o;
}

__device__ inline void gld16(const __bf16* g, __bf16* l) {
    __builtin_amdgcn_global_load_lds((const __attribute__((address_space(1))) void*)g,
                                     (__attribute__((address_space(3))) void*)l, 16, 0, 0);
}

// ---------------------------------------------------------------- gemm8: counted-vmcnt 2-phase pipeline
// 8 waves (2M x 4N), BM=128, BK=32, QUAD-buffered LDS (stage 3 K-tiles ahead).
// Grid exactly 256 blocks (16x16 tiles, 1 per CU) at both call sites.
// Per K-tile, TWO barrier-bounded MFMA clusters (m201 phase pattern):
//   ph1: ds_read af[0..FM) + bfr[0..FN/2), A-gld, BAR, FM*(FN/2) MFMA, BAR
//   ph2: ds_read bfr[FN/2..FN), B-glds,    BAR, FM*(FN/2) MFMA, vmcnt(N), BAR
// Steady-state vmcnt(2*GPK) once per K-tile — never drained to 0 in the loop (T4).
// LDS swizzle: physical 16B granule = logical ^ ((row>>1)&3) (T2); staging keeps the LDS
// dest linear and pre-swizzles the GLOBAL source (rule 21). s_setprio around MFMA (T5).
constexpr int GBK = 32, GBM = 128;

template <typename OutT, int GBN>
__global__ __launch_bounds__(512, 2) void gemm8(const __bf16* __restrict__ A,
                                                const __bf16* __restrict__ B,
                                                OutT* __restrict__ C,
                                                int M, int N, int K, int nbx) {
    constexpr int FM  = 4;                   // M frags / wave (wave tile 64 x (GBN/4))
    constexpr int FN  = GBN / 64;            // N frags / wave
    constexpr int SH  = FN / 2;              // phase split point
    constexpr int AL  = GBM / 128;           // A glds / thread / kt  (=1)
    constexpr int BL  = GBN / 128;           // B glds / thread / kt
    constexpr int GPK = AL + BL;
    constexpr int ASZ = GBM * GBK;
    constexpr int BSZ = GBN * GBK;

    __shared__ __align__(16) __bf16 Ab[4][ASZ];
    __shared__ __align__(16) __bf16 Bb[4][BSZ];

    const int tid = threadIdx.x, w = tid >> 6, lane = tid & 63;
    const int lr = lane & 15, g = lane >> 4;

    // XCD-chunked 2D swizzle: each XCD owns a 4x8 region of the 16x16 tile grid
    const int nwg = (int)gridDim.x;
    const int bid = (int)blockIdx.x;
    int trow, tcol;
    if (nwg == 256 && nbx == 16) {
        const int xcd = bid & 7, j = bid >> 3;       // j in [0,32)
        trow = (xcd >> 1) * 4 + (j >> 3);
        tcol = (xcd & 1) * 8 + (j & 7);
    } else {
        const int id2 = (bid & 7) * (nwg >> 3) + (bid >> 3);
        trow = id2 / nbx; tcol = id2 % nbx;
    }
    const int m0 = trow * GBM, n0 = tcol * GBN;

    const int wm = (w >> 2) * 64, wn = (w & 3) * (GBN / 4);

    // staging: linear LDS dest (G*16B), pre-swizzled global source
    const __bf16* ga[AL]; int la[AL];
    const __bf16* gb[BL]; int lb[BL];
#pragma unroll
    for (int a = 0; a < AL; a++) {
        int G = a * 512 + tid, row = G >> 2;
        int lg = (G & 3) ^ ((row >> 1) & 3);
        ga[a] = A + (size_t)(m0 + row) * K + lg * 8;
        la[a] = G * 8;
    }
#pragma unroll
    for (int b = 0; b < BL; b++) {
        int G = b * 512 + tid, row = G >> 2;
        int lg = (G & 3) ^ ((row >> 1) & 3);
        gb[b] = B + (size_t)(n0 + row) * K + lg * 8;
        lb[b] = G * 8;
    }

    // fragment read offsets: (row>>1)&3 == (lr>>1)&3 for row = wm/wn + frag*16 + lr
    int pao[FM], pbo[FN];
    const int sw = (lr >> 1) & 3;
#pragma unroll
    for (int i = 0; i < FM; i++) pao[i] = (wm + i * 16 + lr) * GBK + ((g ^ sw) * 8);
#pragma unroll
    for (int j = 0; j < FN; j++) pbo[j] = (wn + j * 16 + lr) * GBK + ((g ^ sw) * 8);

    f32x4 acc[FM][FN];
#pragma unroll
    for (int i = 0; i < FM; i++)
#pragma unroll
        for (int j = 0; j < FN; j++) acc[i][j] = (f32x4)(0.f);

    const int NT = K / GBK;

    // prologue: stage kt 0,1,2 into bufs 0,1,2; wait until tile 0 landed
#pragma unroll
    for (int z = 0; z < 3; z++) {
#pragma unroll
        for (int a = 0; a < AL; a++) gld16(ga[a] + z * GBK, &Ab[z][la[a]]);
#pragma unroll
        for (int b = 0; b < BL; b++) gld16(gb[b] + z * GBK, &Bb[z][lb[b]]);
    }
    if constexpr (GPK == 4) asm volatile("s_waitcnt vmcnt(8)" ::: "memory");
    else                    asm volatile("s_waitcnt vmcnt(6)" ::: "memory");
    __builtin_amdgcn_s_barrier();

    for (int Z = 0; Z < NT; ++Z) {
        const int q = Z & 3, qs = (Z + 3) & 3;
        const bool stg = Z < NT - 3;

        bf16x8 af[FM], bfr[FN];
        // ---- phase 1: A frags + first half of B frags; A staging
#pragma unroll
        for (int i = 0; i < FM; i++) af[i] = *(const bf16x8*)&Ab[q][pao[i]];
#pragma unroll
        for (int j = 0; j < SH; j++) bfr[j] = *(const bf16x8*)&Bb[q][pbo[j]];
        if (stg) {
#pragma unroll
            for (int a = 0; a < AL; a++) gld16(ga[a] + (Z + 3) * GBK, &Ab[qs][la[a]]);
        }
        __builtin_amdgcn_s_barrier();
        __builtin_amdgcn_s_setprio(1);
#pragma unroll
        for (int i = 0; i < FM; i++)
#pragma unroll
            for (int j = 0; j < SH; j++)
                acc[i][j] = __builtin_amdgcn_mfma_f32_16x16x32_bf16(
                    af[i], bfr[j], acc[i][j], 0, 0, 0);
        __builtin_amdgcn_s_setprio(0);
        __builtin_amdgcn_s_barrier();

        // ---- phase 2: second half of B frags; B staging; counted vmcnt
#pragma unroll
        for (int j = SH; j < FN; j++) bfr[j] = *(const bf16x8*)&Bb[q][pbo[j]];
        if (stg) {
#pragma unroll
            for (int b = 0; b < BL; b++) gld16(gb[b] + (Z + 3) * GBK, &Bb[qs][lb[b]]);
        }
        __builtin_amdgcn_s_barrier();
        __builtin_amdgcn_s_setprio(1);
#pragma unroll
        for (int i = 0; i < FM; i++)
#pragma unroll
            for (int j = SH; j < FN; j++)
                acc[i][j] = __builtin_amdgcn_mfma_f32_16x16x32_bf16(
                    af[i], bfr[j], acc[i][j], 0, 0, 0);
        __builtin_amdgcn_s_setprio(0);

        if (Z < NT - 3) {
            if constexpr (GPK == 4) asm volatile("s_waitcnt vmcnt(8)" ::: "memory");
            else                    asm volatile("s_waitcnt vmcnt(6)" ::: "memory");
        } else if (Z == NT - 3) {
            if constexpr (GPK == 4) asm volatile("s_waitcnt vmcnt(4)" ::: "memory");
            else                    asm volatile("s_waitcnt vmcnt(3)" ::: "memory");
        } else if (Z == NT - 2) {
            asm volatile("s_waitcnt vmcnt(0)" ::: "memory");
        }
        __builtin_amdgcn_s_barrier();
    }

    const int cr = g * 4, cc = lr;
#pragma unroll
    for (int i = 0; i < FM; i++)
#pragma unroll
        for (int j = 0; j < FN; j++) {
            OutT* Cp = C + (size_t)(m0 + wm + i * 16 + cr) * N + (n0 + wn + j * 16 + cc);
#pragma unroll
            for (int r = 0; r < 4; r++) Cp[(size_t)r * N] = (OutT)acc[i][j][r];
        }
}

// ---------------------------------------------------------------- RoPE in-place on qkv bf16 [S, 6144]
// vectorized bf16x8 loads + native exp2/sin/cos (no libcalls).
__global__ void rope_qkv(__bf16* __restrict__ qkv) {
    int idx  = blockIdx.x * 256 + threadIdx.x;   // S * 40 * 8
    int d8   = idx & 7;
    int rest = idx >> 3;
    int hh   = rest % (kNH + kNKV);
    int s    = rest / (kNH + kNKV);
    __bf16* base = qkv + (size_t)s * kQKV + ((hh < kNH) ? hh * kHD : kKOff + (hh - kNH) * kHD);
    float sc = (hh < kNH) ? 0.088388347648318447f : 1.0f;
    bf16x8 va = *(const bf16x8*)(base + d8 * 8);
    bf16x8 vb = *(const bf16x8*)(base + 64 + d8 * 8);
    bf16x8 ra, rb;
#pragma unroll
    for (int j = 0; j < 8; j++) {
        int d = d8 * 8 + j;
        float rev = (float)s * exp2f(fmaf((float)d, -0.2958057589f, -2.6514961295f));
        rev -= floorf(rev);
        float ang = rev * 6.28318530718f;
        float sn = __sinf(ang), cs = __cosf(ang);
        float a = (float)va[j], b = (float)vb[j];
        ra[j] = (__bf16)((a * cs - b * sn) * sc);
        rb[j] = (__bf16)((b * cs + a * sn) * sc);
    }
    *(bf16x8*)(base + d8 * 8)      = ra;
    *(bf16x8*)(base + 64 + d8 * 8) = rb;
}

// ---------------------------------------------------------------- MFMA flash attention (GQA)
constexpr int VTP = 72;    // Vt row stride elems

__global__ __launch_bounds__(256) void flash_attn(const __bf16* __restrict__ qkv,
                                                  __bf16* __restrict__ ob) {
    __shared__ __align__(16) __bf16 Ks[64 * 128];        // 16 KB, swizzled
    __shared__ __align__(16) __bf16 Vt[128 * VTP];       // 18 KB
    __shared__ __align__(16) __bf16 Ps[4 * 16 * 64];     // 8 KB, swizzled

    const int tid  = threadIdx.x;
    const int wave = tid >> 6, lane = tid & 63;
    const int bx   = blockIdx.x;
    const int kvh  = bx & 7;
    const int qt   = 127 - (bx >> 3);              // heavy tiles first
    const int h    = kvh * 4 + wave;
    const int r    = lane & 15, g = lane >> 4;
    const int r7   = r & 7;
    const int qglob = qt * 16 + r;

    __bf16* Pw = Ps + wave * 16 * 64;
    const __bf16* kbase = qkv + kKOff + kvh * kHD;
    const __bf16* vbase = qkv + kVOff + kvh * kHD;

    int krow[4], kgc[4];
#pragma unroll
    for (int c = 0; c < 4; c++) {
        krow[c] = wave * 16 + c * 4 + (lane >> 4);
        kgc[c]  = (lane & 15) ^ (krow[c] & 15);
    }

    bf16x8 qfrag[4];
    const __bf16* qrow = qkv + (size_t)(qt * 16 + r) * kQKV + h * kHD + g * 8;
#pragma unroll
    for (int c = 0; c < 4; c++) qfrag[c] = *(const bf16x8*)(qrow + c * 32);

    f32x4 o[8];
#pragma unroll
    for (int dt = 0; dt < 8; dt++) o[dt] = (f32x4)(0.f);
    float mrow = -3.0e38f, lrow = 0.f;

    const int nkt = qt / 4 + 1;
    for (int kt = 0; kt < nkt; ++kt) {
#pragma unroll
        for (int c = 0; c < 4; c++)
            gld16(kbase + (size_t)(kt * 64 + krow[c]) * kQKV + kgc[c] * 8,
                  Ks + (wave * 4 + c) * 512);
#pragma unroll
        for (int i = 0; i < 2; i++) {
            int task = i * 256 + tid;
            int p = task & 31, c = task >> 5;
            const __bf16* v0 = vbase + (size_t)(kt * 64 + 2 * p) * kQKV + c * 8;
            u16x8 a = __builtin_bit_cast(u16x8, *(const bf16x8*)v0);
            u16x8 b = __builtin_bit_cast(u16x8, *(const bf16x8*)(v0 + kQKV));
#pragma unroll
            for (int j = 0; j < 8; j++) {
                unsigned int pk = (unsigned int)a[j] | ((unsigned int)b[j] << 16);
                *(unsigned int*)(Vt + (c * 8 + j) * VTP + 2 * p) = pk;
            }
        }
        __syncthreads();

        f32x4 st[4];
#pragma unroll
        for (int t = 0; t < 4; t++) st[t] = (f32x4)(0.f);
#pragma unroll
        for (int c = 0; c < 4; c++) {
#pragma unroll
            for (int t = 0; t < 4; t++) {
                bf16x8 kf = *(const bf16x8*)&Ks[(t * 16 + r) * 128 + (((c * 4 + g) ^ r) * 8)];
                st[t] = __builtin_amdgcn_mfma_f32_16x16x32_bf16(kf, qfrag[c], st[t], 0, 0, 0);
            }
        }

        if (kt == nkt - 1) {
#pragma unroll
            for (int t = 0; t < 4; t++)
#pragma unroll
                for (int reg = 0; reg < 4; reg++) {
                    int key = kt * 64 + t * 16 + g * 4 + reg;
                    if (key > qglob) st[t][reg] = -3.0e38f;
                }
        }

        float mloc = -3.0e38f;
#pragma unroll
        for (int t = 0; t < 4; t++)
#pragma unroll
            for (int reg = 0; reg < 4; reg++) mloc = fmaxf(mloc, st[t][reg]);
        mloc = fmaxf(mloc, __shfl_xor(mloc, 16));
        mloc = fmaxf(mloc, __shfl_xor(mloc, 32));
        float mnew  = fmaxf(mrow, mloc);
        float alpha = __expf(mrow - mnew);
        mrow = mnew;
        float lsum = 0.f;
#pragma unroll
        for (int t = 0; t < 4; t++)
#pragma unroll
            for (int reg = 0; reg < 4; reg++) {
                float pv = __expf(st[t][reg] - mnew);
                st[t][reg] = pv;
                lsum += pv;
            }
        lsum += __shfl_xor(lsum, 16);
        lsum += __shfl_xor(lsum, 32);
        lrow = lrow * alpha + lsum;

        float ar[4];
#pragma unroll
        for (int reg = 0; reg < 4; reg++) ar[reg] = __shfl(alpha, g * 4 + reg);
#pragma unroll
        for (int dt = 0; dt < 8; dt++)
#pragma unroll
            for (int reg = 0; reg < 4; reg++) o[dt][reg] *= ar[reg];

#pragma unroll
        for (int t = 0; t < 4; t++) {
            bf16x4 pb;
#pragma unroll
            for (int j = 0; j < 4; j++) pb[j] = (__bf16)st[t][j];
            int p8 = t * 4 + g;
            *(bf16x4*)&Pw[r * 64 + (((p8 >> 1) ^ r7) * 8) + ((p8 & 1) * 4)] = pb;
        }
        __asm__ volatile("s_waitcnt lgkmcnt(0)" ::: "memory");

#pragma unroll
        for (int kc = 0; kc < 2; kc++) {
            bf16x8 pf = *(const bf16x8*)&Pw[r * 64 + (((kc * 4 + g) ^ r7) * 8)];
#pragma unroll
            for (int dt = 0; dt < 8; dt++) {
                bf16x8 vf = *(const bf16x8*)&Vt[(dt * 16 + r) * VTP + kc * 32 + g * 8];
                o[dt] = __builtin_amdgcn_mfma_f32_16x16x32_bf16(pf, vf, o[dt], 0, 0, 0);
            }
        }
        __syncthreads();
    }

    float linv = 1.f / lrow;
    float lr4[4];
#pragma unroll
    for (int reg = 0; reg < 4; reg++) lr4[reg] = __shfl(linv, g * 4 + reg);
#pragma unroll
    for (int dt = 0; dt < 8; dt++)
#pragma unroll
        for (int reg = 0; reg < 4; reg++) {
            int qq = g * 4 + reg, dd = dt * 16 + r;
            ob[(size_t)(qt * 16 + qq) * kH + h * kHD + dd] = (__bf16)(o[dt][reg] * lr4[reg]);
        }
}

// ---------------------------------------------------------------- launch
extern "C" void kernel_launch(void* const* d_in, const int* in_sizes, int n_in,
                              void* d_out, int out_size, void* d_ws, size_t ws_size,
                              hipStream_t stream) {
    const float* x  = (const float*)d_in[0];
    const float* wq = (const float*)d_in[1];
    const float* wk = (const float*)d_in[2];
    const float* wv = (const float*)d_in[3];
    const float* wo = (const float*)d_in[4];
    float* out = (float*)d_out;

    char* p = (char*)d_ws;
    auto alloc = [&](size_t bytes) {
        char* r = p;
        p += (bytes + 255) & ~(size_t)255;
        return r;
    };
    __bf16* xb    = (__bf16*)alloc((size_t)kS * kH * 2);        // 16 MB; later attn out
    __bf16* wqkvb = (__bf16*)alloc((size_t)kQKV * kH * 2);      // 48 MB; later wo bf16
    __bf16* qkv   = (__bf16*)alloc((size_t)kS * kQKV * 2);      // 24 MB
    __bf16* ao    = xb;
    __bf16* wob   = wqkvb;

    cast_all<<<dim3(1 << 15), 256, 0, stream>>>(x, wq, wk, wv, xb, wqkvb);

    // QKV GEMM: 128x384 tiles -> 16x16 = 256 blocks (exactly 1 per CU)
    gemm8<__bf16, 384><<<dim3((kS / GBM) * (kQKV / 384)), 512, 0, stream>>>(
        xb, wqkvb, qkv, kS, kQKV, kH, kQKV / 384);

    rope_qkv<<<dim3(kS * (kNH + kNKV) * 8 / 256), 256, 0, stream>>>(qkv);

    cast_bf16<<<dim3((kH * kH / 4) / 256), 256, 0, stream>>>(wo, wob, kH * kH / 4);

    flash_attn<<<dim3(kNKV * (kS / 16)), 256, 0, stream>>>(qkv, ao);

    // proj GEMM: 128x256 tiles -> 16x16 = 256 blocks (exactly 1 per CU)
    gemm8<float, 256><<<dim3((kS / GBM) * (kH / 256)), 512, 0, stream>>>(
        ao, wob, out, kS, kH, kH, kH / 256);
}

// Round 6
// 472.063 us; speedup vs baseline: 1.0353x; 1.0353x over previous
//
#include <hip/hip_runtime.h>
#include <hip/hip_bf16.h>
#include <math.h>

typedef __bf16 bf16x8 __attribute__((ext_vector_type(8)));
typedef __bf16 bf16x4 __attribute__((ext_vector_type(4)));
typedef unsigned short u16x8 __attribute__((ext_vector_type(8)));
typedef float  f32x4  __attribute__((ext_vector_type(4)));

constexpr int kS   = 2048;
constexpr int kH   = 4096;
constexpr int kNH  = 32;
constexpr int kNKV = 8;
constexpr int kHD  = 128;
constexpr int kQKV = kH + 2 * kNKV * kHD;   // 6144: [Q 4096 | K 1024 | V 1024]
constexpr int kKOff = kH;                    // 4096
constexpr int kVOff = kH + kNKV * kHD;       // 5120

// ---------------------------------------------------------------- generic cast
__global__ void cast_bf16(const float* __restrict__ in, __bf16* __restrict__ out, int n4) {
    int i = blockIdx.x * blockDim.x + threadIdx.x;
    if (i < n4) {
        float4 f = ((const float4*)in)[i];
        bf16x4 o;
        o[0] = (__bf16)f.x; o[1] = (__bf16)f.y; o[2] = (__bf16)f.z; o[3] = (__bf16)f.w;
        ((bf16x4*)out)[i] = o;
    }
}

// ---------------------------------------------------------------- fused cast: x -> xb, wq|wk|wv -> wqkv
__global__ void cast_all(const float* __restrict__ x, const float* __restrict__ wq,
                         const float* __restrict__ wk, const float* __restrict__ wv,
                         __bf16* __restrict__ xb, __bf16* __restrict__ wqkv) {
    int i = blockIdx.x * 256 + threadIdx.x;
    float4 f;
    __bf16* dst;
    int di;
    if (i < (1 << 21)) {
        f = ((const float4*)x)[i];
        dst = xb; di = i;
    } else {
        int j = i - (1 << 21);
        const float4* s = (j < (1 << 22)) ? ((const float4*)wq + j)
                        : (j < (5 << 20)) ? ((const float4*)wk + (j - (1 << 22)))
                                          : ((const float4*)wv + (j - (5 << 20)));
        f = *s;
        dst = wqkv; di = j;
    }
    bf16x4 o;
    o[0] = (__bf16)f.x; o[1] = (__bf16)f.y; o[2] = (__bf16)f.z; o[3] = (__bf16)f.w;
    ((bf16x4*)dst)[di] = o;
}

__device__ inline void gld16(const __bf16* g, __bf16* l) {
    __builtin_amdgcn_global_load_lds((const __attribute__((address_space(1))) void*)g,
                                     (__attribute__((address_space(3))) void*)l, 16, 0, 0);
}

// ---------------------------------------------------------------- gemm8: single-phase counted-vmcnt pipeline
// 8 waves (2M x 4N), BM=128, BK=32, QUAD-buffered LDS (stage 3 K-tiles ahead).
// Grid exactly 256 blocks. Counted vmcnt once per K-tile (T4); T2 swizzle; T5 setprio.
// (round-3 structure + round-4 2D XCD swizzle — both harness-verified)
constexpr int GBK = 32, GBM = 128;

template <typename OutT, int GBN>
__global__ __launch_bounds__(512, 2) void gemm8(const __bf16* __restrict__ A,
                                                const __bf16* __restrict__ B,
                                                OutT* __restrict__ C,
                                                int M, int N, int K, int nbx) {
    constexpr int FM  = 4;
    constexpr int FN  = GBN / 64;
    constexpr int AL  = GBM / 128;
    constexpr int BL  = GBN / 128;
    constexpr int GPK = AL + BL;
    constexpr int ASZ = GBM * GBK;
    constexpr int BSZ = GBN * GBK;

    __shared__ __align__(16) __bf16 Ab[4][ASZ];
    __shared__ __align__(16) __bf16 Bb[4][BSZ];

    const int tid = threadIdx.x, w = tid >> 6, lane = tid & 63;
    const int lr = lane & 15, g = lane >> 4;

    // XCD-chunked 2D swizzle: each XCD owns a 4x8 region of the 16x16 tile grid
    const int nwg = (int)gridDim.x;
    const int bid = (int)blockIdx.x;
    int trow, tcol;
    if (nwg == 256 && nbx == 16) {
        const int xcd = bid & 7, j = bid >> 3;
        trow = (xcd >> 1) * 4 + (j >> 3);
        tcol = (xcd & 1) * 8 + (j & 7);
    } else {
        const int id2 = (bid & 7) * (nwg >> 3) + (bid >> 3);
        trow = id2 / nbx; tcol = id2 % nbx;
    }
    const int m0 = trow * GBM, n0 = tcol * GBN;

    const int wm = (w >> 2) * 64, wn = (w & 3) * (GBN / 4);

    const __bf16* ga[AL]; int la[AL];
    const __bf16* gb[BL]; int lb[BL];
#pragma unroll
    for (int a = 0; a < AL; a++) {
        int G = a * 512 + tid, row = G >> 2;
        int lg = (G & 3) ^ ((row >> 1) & 3);
        ga[a] = A + (size_t)(m0 + row) * K + lg * 8;
        la[a] = G * 8;
    }
#pragma unroll
    for (int b = 0; b < BL; b++) {
        int G = b * 512 + tid, row = G >> 2;
        int lg = (G & 3) ^ ((row >> 1) & 3);
        gb[b] = B + (size_t)(n0 + row) * K + lg * 8;
        lb[b] = G * 8;
    }

    int pao[FM], pbo[FN];
    const int sw = (lr >> 1) & 3;
#pragma unroll
    for (int i = 0; i < FM; i++) pao[i] = (wm + i * 16 + lr) * GBK + ((g ^ sw) * 8);
#pragma unroll
    for (int j = 0; j < FN; j++) pbo[j] = (wn + j * 16 + lr) * GBK + ((g ^ sw) * 8);

    f32x4 acc[FM][FN];
#pragma unroll
    for (int i = 0; i < FM; i++)
#pragma unroll
        for (int j = 0; j < FN; j++) acc[i][j] = (f32x4)(0.f);

    const int NT = K / GBK;

#pragma unroll
    for (int z = 0; z < 3; z++) {
#pragma unroll
        for (int a = 0; a < AL; a++) gld16(ga[a] + z * GBK, &Ab[z][la[a]]);
#pragma unroll
        for (int b = 0; b < BL; b++) gld16(gb[b] + z * GBK, &Bb[z][lb[b]]);
    }
    if constexpr (GPK == 4) asm volatile("s_waitcnt vmcnt(8)" ::: "memory");
    else                    asm volatile("s_waitcnt vmcnt(6)" ::: "memory");
    __builtin_amdgcn_s_barrier();

    for (int Z = 0; Z < NT; ++Z) {
        const int q = Z & 3, qs = (Z + 3) & 3;

        bf16x8 af[FM], bfr[FN];
#pragma unroll
        for (int i = 0; i < FM; i++) af[i]  = *(const bf16x8*)&Ab[q][pao[i]];
#pragma unroll
        for (int j = 0; j < FN; j++) bfr[j] = *(const bf16x8*)&Bb[q][pbo[j]];

        if (Z < NT - 3) {
#pragma unroll
            for (int a = 0; a < AL; a++) gld16(ga[a] + (Z + 3) * GBK, &Ab[qs][la[a]]);
#pragma unroll
            for (int b = 0; b < BL; b++) gld16(gb[b] + (Z + 3) * GBK, &Bb[qs][lb[b]]);
        }

        __builtin_amdgcn_s_barrier();
        __builtin_amdgcn_s_setprio(1);
#pragma unroll
        for (int i = 0; i < FM; i++)
#pragma unroll
            for (int j = 0; j < FN; j++)
                acc[i][j] = __builtin_amdgcn_mfma_f32_16x16x32_bf16(
                    af[i], bfr[j], acc[i][j], 0, 0, 0);
        __builtin_amdgcn_s_setprio(0);

        if (Z < NT - 3) {
            if constexpr (GPK == 4) asm volatile("s_waitcnt vmcnt(8)" ::: "memory");
            else                    asm volatile("s_waitcnt vmcnt(6)" ::: "memory");
        } else if (Z == NT - 3) {
            if constexpr (GPK == 4) asm volatile("s_waitcnt vmcnt(4)" ::: "memory");
            else                    asm volatile("s_waitcnt vmcnt(3)" ::: "memory");
        } else if (Z == NT - 2) {
            asm volatile("s_waitcnt vmcnt(0)" ::: "memory");
        }
        __builtin_amdgcn_s_barrier();
    }

    const int cr = g * 4, cc = lr;
#pragma unroll
    for (int i = 0; i < FM; i++)
#pragma unroll
        for (int j = 0; j < FN; j++) {
            OutT* Cp = C + (size_t)(m0 + wm + i * 16 + cr) * N + (n0 + wn + j * 16 + cc);
#pragma unroll
            for (int r = 0; r < 4; r++) Cp[(size_t)r * N] = (OutT)acc[i][j][r];
        }
}

// ---------------------------------------------------------------- RoPE in-place on qkv bf16 [S, 6144]
__global__ void rope_qkv(__bf16* __restrict__ qkv) {
    int idx  = blockIdx.x * 256 + threadIdx.x;   // S * 40 * 8
    int d8   = idx & 7;
    int rest = idx >> 3;
    int hh   = rest % (kNH + kNKV);
    int s    = rest / (kNH + kNKV);
    __bf16* base = qkv + (size_t)s * kQKV + ((hh < kNH) ? hh * kHD : kKOff + (hh - kNH) * kHD);
    float sc = (hh < kNH) ? 0.088388347648318447f : 1.0f;
    bf16x8 va = *(const bf16x8*)(base + d8 * 8);
    bf16x8 vb = *(const bf16x8*)(base + 64 + d8 * 8);
    bf16x8 ra, rb;
#pragma unroll
    for (int j = 0; j < 8; j++) {
        int d = d8 * 8 + j;
        float rev = (float)s * exp2f(fmaf((float)d, -0.2958057589f, -2.6514961295f));
        rev -= floorf(rev);
        float ang = rev * 6.28318530718f;
        float sn = __sinf(ang), cs = __cosf(ang);
        float a = (float)va[j], b = (float)vb[j];
        ra[j] = (__bf16)((a * cs - b * sn) * sc);
        rb[j] = (__bf16)((b * cs + a * sn) * sc);
    }
    *(bf16x8*)(base + d8 * 8)      = ra;
    *(bf16x8*)(base + 64 + d8 * 8) = rb;
}

// ---------------------------------------------------------------- MFMA flash attention (GQA)
// PIPELINED: double-buffered Ks/Vt, K prefetch via gld16, V issue-early/write-late (T14),
// explicit vmcnt(0) before the V write (deterministic staging drain), ONE barrier per tile.
// Math (QK/softmax/P-pack/PV) identical to the verified round-3 kernel.
constexpr int VTP = 72;    // Vt row stride elems

__global__ __launch_bounds__(256) void flash_attn(const __bf16* __restrict__ qkv,
                                                  __bf16* __restrict__ ob) {
    __shared__ __align__(16) __bf16 Ks[2][64 * 128];     // 32 KB, swizzled
    __shared__ __align__(16) __bf16 Vt[2][128 * VTP];    // 36 KB
    __shared__ __align__(16) __bf16 Ps[4 * 16 * 64];     // 8 KB, swizzled

    const int tid  = threadIdx.x;
    const int wave = tid >> 6, lane = tid & 63;
    const int bx   = blockIdx.x;
    const int kvh  = bx & 7;
    const int qt   = 127 - (bx >> 3);              // heavy tiles first
    const int h    = kvh * 4 + wave;
    const int r    = lane & 15, g = lane >> 4;
    const int r7   = r & 7;
    const int qglob = qt * 16 + r;

    __bf16* Pw = Ps + wave * 16 * 64;
    const __bf16* kbase = qkv + kKOff + kvh * kHD;
    const __bf16* vbase = qkv + kVOff + kvh * kHD;

    // K staging geometry (global_load_lds, slot = chunk ^ (row&15))
    int krow[4], kgc[4];
#pragma unroll
    for (int c = 0; c < 4; c++) {
        krow[c] = wave * 16 + c * 4 + (lane >> 4);
        kgc[c]  = (lane & 15) ^ (krow[c] & 15);
    }
    // V staging geometry: 2 tasks/thread (p: key pair, c: 8-d chunk)
    int vp[2], vc[2];
#pragma unroll
    for (int i = 0; i < 2; i++) {
        int task = i * 256 + tid;
        vp[i] = task & 31; vc[i] = task >> 5;
    }

    bf16x8 qfrag[4];
    const __bf16* qrow = qkv + (size_t)(qt * 16 + r) * kQKV + h * kHD + g * 8;
#pragma unroll
    for (int c = 0; c < 4; c++) qfrag[c] = *(const bf16x8*)(qrow + c * 32);

    f32x4 o[8];
#pragma unroll
    for (int dt = 0; dt < 8; dt++) o[dt] = (f32x4)(0.f);
    float mrow = -3.0e38f, lrow = 0.f;

    const int nkt = qt / 4 + 1;

    // ---- prologue: stage tile 0 into buffer 0
    bf16x8 va[2], vb[2];
#pragma unroll
    for (int c = 0; c < 4; c++)
        gld16(kbase + (size_t)krow[c] * kQKV + kgc[c] * 8, &Ks[0][(wave * 4 + c) * 512]);
#pragma unroll
    for (int i = 0; i < 2; i++) {
        const __bf16* v0 = vbase + (size_t)(2 * vp[i]) * kQKV + vc[i] * 8;
        va[i] = *(const bf16x8*)v0;
        vb[i] = *(const bf16x8*)(v0 + kQKV);
    }
    asm volatile("s_waitcnt vmcnt(0)" ::: "memory");
#pragma unroll
    for (int i = 0; i < 2; i++) {
        u16x8 a = __builtin_bit_cast(u16x8, va[i]);
        u16x8 b = __builtin_bit_cast(u16x8, vb[i]);
#pragma unroll
        for (int j = 0; j < 8; j++) {
            unsigned int pk = (unsigned int)a[j] | ((unsigned int)b[j] << 16);
            *(unsigned int*)(&Vt[0][(vc[i] * 8 + j) * VTP + 2 * vp[i]]) = pk;
        }
    }
    __syncthreads();

    for (int kt = 0; kt < nkt; ++kt) {
        const int cur = kt & 1, nb = cur ^ 1;
        const bool nxt = (kt + 1) < nkt;

        // ---- issue next tile's staging early (K -> LDS[nb] async, V -> regs)
        if (nxt) {
#pragma unroll
            for (int c = 0; c < 4; c++)
                gld16(kbase + (size_t)((kt + 1) * 64 + krow[c]) * kQKV + kgc[c] * 8,
                      &Ks[nb][(wave * 4 + c) * 512]);
#pragma unroll
            for (int i = 0; i < 2; i++) {
                const __bf16* v0 = vbase + (size_t)((kt + 1) * 64 + 2 * vp[i]) * kQKV + vc[i] * 8;
                va[i] = *(const bf16x8*)v0;
                vb[i] = *(const bf16x8*)(v0 + kQKV);
            }
        }

        // ---- S^T = K·Q^T on Ks[cur] (staged last iter, joined by last barrier)
        f32x4 st[4];
#pragma unroll
        for (int t = 0; t < 4; t++) st[t] = (f32x4)(0.f);
#pragma unroll
        for (int c = 0; c < 4; c++) {
#pragma unroll
            for (int t = 0; t < 4; t++) {
                bf16x8 kf = *(const bf16x8*)&Ks[cur][(t * 16 + r) * 128 + (((c * 4 + g) ^ r) * 8)];
                st[t] = __builtin_amdgcn_mfma_f32_16x16x32_bf16(kf, qfrag[c], st[t], 0, 0, 0);
            }
        }

        // ---- causal mask: only the diagonal tile can violate
        if (kt == nkt - 1) {
#pragma unroll
            for (int t = 0; t < 4; t++)
#pragma unroll
                for (int reg = 0; reg < 4; reg++) {
                    int key = kt * 64 + t * 16 + g * 4 + reg;
                    if (key > qglob) st[t][reg] = -3.0e38f;
                }
        }

        // ---- online softmax (per q = r)
        float mloc = -3.0e38f;
#pragma unroll
        for (int t = 0; t < 4; t++)
#pragma unroll
            for (int reg = 0; reg < 4; reg++) mloc = fmaxf(mloc, st[t][reg]);
        mloc = fmaxf(mloc, __shfl_xor(mloc, 16));
        mloc = fmaxf(mloc, __shfl_xor(mloc, 32));
        float mnew  = fmaxf(mrow, mloc);
        float alpha = __expf(mrow - mnew);
        mrow = mnew;
        float lsum = 0.f;
#pragma unroll
        for (int t = 0; t < 4; t++)
#pragma unroll
            for (int reg = 0; reg < 4; reg++) {
                float pv = __expf(st[t][reg] - mnew);
                st[t][reg] = pv;
                lsum += pv;
            }
        lsum += __shfl_xor(lsum, 16);
        lsum += __shfl_xor(lsum, 32);
        lrow = lrow * alpha + lsum;

        float ar[4];
#pragma unroll
        for (int reg = 0; reg < 4; reg++) ar[reg] = __shfl(alpha, g * 4 + reg);
#pragma unroll
        for (int dt = 0; dt < 8; dt++)
#pragma unroll
            for (int reg = 0; reg < 4; reg++) o[dt][reg] *= ar[reg];

        // ---- late half of staging: drain all vmem (K glds + V loads), write V -> Vt[nb]
        if (nxt) {
            asm volatile("s_waitcnt vmcnt(0)" ::: "memory");
#pragma unroll
            for (int i = 0; i < 2; i++) {
                u16x8 a = __builtin_bit_cast(u16x8, va[i]);
                u16x8 b = __builtin_bit_cast(u16x8, vb[i]);
#pragma unroll
                for (int j = 0; j < 8; j++) {
                    unsigned int pk = (unsigned int)a[j] | ((unsigned int)b[j] << 16);
                    *(unsigned int*)(&Vt[nb][(vc[i] * 8 + j) * VTP + 2 * vp[i]]) = pk;
                }
            }
        }

        // ---- P (bf16): C-layout -> LDS -> A-layout, XOR-swizzled 8B slots
#pragma unroll
        for (int t = 0; t < 4; t++) {
            bf16x4 pb;
#pragma unroll
            for (int j = 0; j < 4; j++) pb[j] = (__bf16)st[t][j];
            int p8 = t * 4 + g;
            *(bf16x4*)&Pw[r * 64 + (((p8 >> 1) ^ r7) * 8) + ((p8 & 1) * 4)] = pb;
        }
        __asm__ volatile("s_waitcnt lgkmcnt(0)" ::: "memory");

        // ---- PV on Vt[cur]
#pragma unroll
        for (int kc = 0; kc < 2; kc++) {
            bf16x8 pf = *(const bf16x8*)&Pw[r * 64 + (((kc * 4 + g) ^ r7) * 8)];
#pragma unroll
            for (int dt = 0; dt < 8; dt++) {
                bf16x8 vf = *(const bf16x8*)&Vt[cur][(dt * 16 + r) * VTP + kc * 32 + g * 8];
                o[dt] = __builtin_amdgcn_mfma_f32_16x16x32_bf16(pf, vf, o[dt], 0, 0, 0);
            }
        }
        __syncthreads();
    }

    // ---- epilogue
    float linv = 1.f / lrow;
    float lr4[4];
#pragma unroll
    for (int reg = 0; reg < 4; reg++) lr4[reg] = __shfl(linv, g * 4 + reg);
#pragma unroll
    for (int dt = 0; dt < 8; dt++)
#pragma unroll
        for (int reg = 0; reg < 4; reg++) {
            int qq = g * 4 + reg, dd = dt * 16 + r;
            ob[(size_t)(qt * 16 + qq) * kH + h * kHD + dd] = (__bf16)(o[dt][reg] * lr4[reg]);
        }
}

// ---------------------------------------------------------------- launch
extern "C" void kernel_launch(void* const* d_in, const int* in_sizes, int n_in,
                              void* d_out, int out_size, void* d_ws, size_t ws_size,
                              hipStream_t stream) {
    const float* x  = (const float*)d_in[0];
    const float* wq = (const float*)d_in[1];
    const float* wk = (const float*)d_in[2];
    const float* wv = (const float*)d_in[3];
    const float* wo = (const float*)d_in[4];
    float* out = (float*)d_out;

    char* p = (char*)d_ws;
    auto alloc = [&](size_t bytes) {
        char* r = p;
        p += (bytes + 255) & ~(size_t)255;
        return r;
    };
    __bf16* xb    = (__bf16*)alloc((size_t)kS * kH * 2);        // 16 MB; later attn out
    __bf16* wqkvb = (__bf16*)alloc((size_t)kQKV * kH * 2);      // 48 MB; later wo bf16
    __bf16* qkv   = (__bf16*)alloc((size_t)kS * kQKV * 2);      // 24 MB
    __bf16* ao    = xb;
    __bf16* wob   = wqkvb;

    cast_all<<<dim3(1 << 15), 256, 0, stream>>>(x, wq, wk, wv, xb, wqkvb);

    // QKV GEMM: 128x384 tiles -> 16x16 = 256 blocks (exactly 1 per CU)
    gemm8<__bf16, 384><<<dim3((kS / GBM) * (kQKV / 384)), 512, 0, stream>>>(
        xb, wqkvb, qkv, kS, kQKV, kH, kQKV / 384);

    rope_qkv<<<dim3(kS * (kNH + kNKV) * 8 / 256), 256, 0, stream>>>(qkv);

    cast_bf16<<<dim3((kH * kH / 4) / 256), 256, 0, stream>>>(wo, wob, kH * kH / 4);

    flash_attn<<<dim3(kNKV * (kS / 16)), 256, 0, stream>>>(qkv, ao);

    // proj GEMM: 128x256 tiles -> 16x16 = 256 blocks (exactly 1 per CU)
    gemm8<float, 256><<<dim3((kS / GBM) * (kH / 256)), 512, 0, stream>>>(
        ao, wob, out, kS, kH, kH, kH / 256);
}